// Round 4
// baseline (494.142 us; speedup 1.0000x reference)
//
#include <hip/hip_runtime.h>

// Qwen3 MoE experts: per-expert SwiGLU MLP.
//   gate = rin @ gate_proj^T ; up = rin @ up_proj^T
//   hidden = silu(gate) * up ; out = hidden @ down_proj^T
// E=32, T=512, H=2048, I=768. f32 inputs; bf16 MFMA, f32 accum.
// ws: hidden [E][T][I] bf16 = 24 MB.
//
// R3: T3/T4 — double-buffered LDS + counted vmcnt. Stage tile k+1 via
//     global_load_lds while computing tile k; wait vmcnt(12)/(6) (count of
//     just-issued loads), never 0 in the main loop. lgkmcnt(0)+sched_barrier
//     before barrier B so no wave crosses with ds_reads in flight (rule 18).

#define NE 32
#define NT 512
#define NH 2048
#define NI 768

typedef short        short8  __attribute__((ext_vector_type(8)));
typedef float        floatx4 __attribute__((ext_vector_type(4)));
typedef __attribute__((address_space(1))) const unsigned int g_u32;
typedef __attribute__((address_space(3))) unsigned int l_u32;

__device__ __forceinline__ void gl_lds16(const void* g, void* l) {
    __builtin_amdgcn_global_load_lds((g_u32*)g, (l_u32*)l, 16, 0, 0);
}

__device__ __forceinline__ unsigned int cvt_pk_bf16(float lo, float hi) {
    unsigned int r;
    asm("v_cvt_pk_bf16_f32 %0, %1, %2" : "=v"(r) : "v"(lo), "v"(hi));
    return r;
}

__device__ __forceinline__ short8 frag8(floatx4 x0, floatx4 x1) {
    union { unsigned int u[4]; short8 s; } t;
    t.u[0] = cvt_pk_bf16(x0[0], x0[1]);
    t.u[1] = cvt_pk_bf16(x0[2], x0[3]);
    t.u[2] = cvt_pk_bf16(x1[0], x1[1]);
    t.u[3] = cvt_pk_bf16(x1[2], x1[3]);
    return t.s;
}

__device__ __forceinline__ ushort f2bf(float f) {
    union { float f; unsigned int u; } v; v.f = f;
    unsigned int r = v.u + 0x7fffu + ((v.u >> 16) & 1u);
    return (ushort)(r >> 16);
}

// ---------------------------------------------------------------------------
// Kernel 1: fused gate+up + SwiGLU -> hidden(bf16).
// BM=128(T) x BN=128(I), BK=32 over H; 4 waves (2x2), 64x64/wave.
// LDS: 2 x (3 x f32[128][32]) = 96 KB (1 block/CU), source-XOR-swizzled.
// ---------------------------------------------------------------------------
__global__ __launch_bounds__(256, 1) void moe_gateup(
    const float* __restrict__ rin, const float* __restrict__ gate,
    const float* __restrict__ up, ushort* __restrict__ hidden)
{
    __shared__ float As[2][128][32];
    __shared__ float Gs[2][128][32];
    __shared__ float Us[2][128][32];

    const int bid = blockIdx.x;
    const int wg  = (bid & 7) * (768 / 8) + (bid >> 3);
    const int e   = wg / 24;
    const int rem = wg % 24;
    const int ti  = rem % 6;
    const int tm  = rem / 6;

    const int tid  = threadIdx.x;
    const int lane = tid & 63;
    const int wave = tid >> 6;
    const int wr = wave >> 1, wc = wave & 1;

    const float* Ab = rin  + (size_t)e * NT * NH + (size_t)(tm * 128) * NH;
    const float* Gb = gate + (size_t)e * NI * NH + (size_t)(ti * 128) * NH;
    const float* Ub = up   + (size_t)e * NI * NH + (size_t)(ti * 128) * NH;

    const int lr = lane >> 3;
    const int lc = lane & 7;

    floatx4 accg[4][4], accu[4][4];
    #pragma unroll
    for (int m = 0; m < 4; ++m)
        #pragma unroll
        for (int n = 0; n < 4; ++n) {
            accg[m][n] = (floatx4)0.f;
            accu[m][n] = (floatx4)0.f;
        }

    const int frow = lane & 15;
    const int h    = lane >> 4;
    const int rb   = frow & 7;
    const int c0   = (2 * h) ^ rb;
    const int c1   = (2 * h + 1) ^ rb;
    const int KT = NH / 32;

    // 12 global_load_lds per wave per stage
#define STAGE_GU(kt, b) do {                                                 \
        const int k0_ = (kt) * 32;                                           \
        _Pragma("unroll")                                                    \
        for (int i = 0; i < 4; ++i) {                                        \
            const int g_ = wave * 4 + i;                                     \
            const int r_ = g_ * 8 + lr;                                      \
            const int cs_ = lc ^ (r_ & 7);                                   \
            const size_t so_ = (size_t)r_ * NH + k0_ + cs_ * 4;              \
            gl_lds16(Ab + so_, &As[b][g_ * 8][0]);                           \
            gl_lds16(Gb + so_, &Gs[b][g_ * 8][0]);                           \
            gl_lds16(Ub + so_, &Us[b][g_ * 8][0]);                           \
        }                                                                    \
    } while (0)

    STAGE_GU(0, 0);

    for (int kt = 0; kt < KT; ++kt) {
        const int cur = kt & 1;
        if (kt + 1 < KT) {
            STAGE_GU(kt + 1, cur ^ 1);
            asm volatile("s_waitcnt vmcnt(12)" ::: "memory");  // tile kt landed
        } else {
            asm volatile("s_waitcnt vmcnt(0)" ::: "memory");
        }
        __builtin_amdgcn_s_barrier();   // A: tile kt visible to all waves

        short8 af[4], gf[4], uf[4];
        #pragma unroll
        for (int m = 0; m < 4; ++m) {
            const int R = wr * 64 + m * 16 + frow;
            af[m] = frag8(*(const floatx4*)&As[cur][R][c0 * 4],
                          *(const floatx4*)&As[cur][R][c1 * 4]);
        }
        #pragma unroll
        for (int n = 0; n < 4; ++n) {
            const int R = wc * 64 + n * 16 + frow;
            gf[n] = frag8(*(const floatx4*)&Gs[cur][R][c0 * 4],
                          *(const floatx4*)&Gs[cur][R][c1 * 4]);
            uf[n] = frag8(*(const floatx4*)&Us[cur][R][c0 * 4],
                          *(const floatx4*)&Us[cur][R][c1 * 4]);
        }
        #pragma unroll
        for (int m = 0; m < 4; ++m)
            #pragma unroll
            for (int n = 0; n < 4; ++n) {
                accg[m][n] = __builtin_amdgcn_mfma_f32_16x16x32_bf16(
                    af[m], gf[n], accg[m][n], 0, 0, 0);
                accu[m][n] = __builtin_amdgcn_mfma_f32_16x16x32_bf16(
                    af[m], uf[n], accu[m][n], 0, 0, 0);
            }

        asm volatile("s_waitcnt lgkmcnt(0)" ::: "memory");  // ds_reads done
        __builtin_amdgcn_sched_barrier(0);
        __builtin_amdgcn_s_barrier();   // B: buf[cur] free for overwrite
    }
#undef STAGE_GU

    const int ccol  = lane & 15;
    const int crow0 = (lane >> 4) * 4;
    const size_t hbase = ((size_t)e * NT + (size_t)tm * 128) * NI + ti * 128;
    #pragma unroll
    for (int m = 0; m < 4; ++m)
        #pragma unroll
        for (int n = 0; n < 4; ++n)
            #pragma unroll
            for (int j = 0; j < 4; ++j) {
                const float g = accg[m][n][j];
                const float u = accu[m][n][j];
                const float hh = (g / (1.f + __expf(-g))) * u;
                const int row = wr * 64 + m * 16 + crow0 + j;
                const int col = wc * 64 + n * 16 + ccol;
                hidden[hbase + (size_t)row * NI + col] = f2bf(hh);
            }
}

// ---------------------------------------------------------------------------
// Kernel 2: down projection. A = hidden [T,I] bf16, B = down [H,I] f32.
// LDS: 2 x (ushort A[128][32] + f32 B[128][32]) = 48 KB.
// ---------------------------------------------------------------------------
__global__ __launch_bounds__(256, 2) void moe_down(
    const ushort* __restrict__ hidden, const float* __restrict__ down,
    float* __restrict__ out)
{
    __shared__ ushort As[2][128][32];
    __shared__ float  Bs[2][128][32];

    const int bid = blockIdx.x;
    const int wg  = (bid & 7) * (2048 / 8) + (bid >> 3);
    const int e   = wg >> 6;
    const int rem = wg & 63;
    const int tn  = rem & 15;
    const int tm  = rem >> 4;

    const int tid  = threadIdx.x;
    const int lane = tid & 63;
    const int wave = tid >> 6;
    const int wr = wave >> 1, wc = wave & 1;

    const ushort* Ab = hidden + ((size_t)e * NT + (size_t)tm * 128) * NI;
    const float*  Bb = down + (size_t)e * NH * NI + (size_t)(tn * 128) * NI;

    floatx4 acc[4][4];
    #pragma unroll
    for (int m = 0; m < 4; ++m)
        #pragma unroll
        for (int n = 0; n < 4; ++n) acc[m][n] = (floatx4)0.f;

    const int frow = lane & 15;
    const int h    = lane >> 4;
    const int ca   = h ^ (frow & 3);
    const int rb   = frow & 7;
    const int c0   = (2 * h) ^ rb;
    const int c1   = (2 * h + 1) ^ rb;
    const int KT = NI / 32;

    // 6 global_load_lds per wave per stage (2 A + 4 B)
#define STAGE_DN(kt, b) do {                                                 \
        const int k0_ = (kt) * 32;                                           \
        _Pragma("unroll")                                                    \
        for (int i = 0; i < 2; ++i) {                                        \
            const int g_ = wave * 2 + i;                                     \
            const int r_ = g_ * 16 + (lane >> 2);                            \
            const int cs_ = (lane & 3) ^ (r_ & 3);                           \
            gl_lds16(Ab + (size_t)r_ * NI + k0_ + cs_ * 8, &As[b][g_ * 16][0]); \
        }                                                                    \
        _Pragma("unroll")                                                    \
        for (int i = 0; i < 4; ++i) {                                        \
            const int g_ = wave * 4 + i;                                     \
            const int r_ = g_ * 8 + (lane >> 3);                             \
            const int cs_ = (lane & 7) ^ (r_ & 7);                           \
            gl_lds16(Bb + (size_t)r_ * NI + k0_ + cs_ * 4, &Bs[b][g_ * 8][0]); \
        }                                                                    \
    } while (0)

    STAGE_DN(0, 0);

    for (int kt = 0; kt < KT; ++kt) {
        const int cur = kt & 1;
        if (kt + 1 < KT) {
            STAGE_DN(kt + 1, cur ^ 1);
            asm volatile("s_waitcnt vmcnt(6)" ::: "memory");
        } else {
            asm volatile("s_waitcnt vmcnt(0)" ::: "memory");
        }
        __builtin_amdgcn_s_barrier();

        short8 af[4], bf[4];
        #pragma unroll
        for (int m = 0; m < 4; ++m) {
            const int R = wr * 64 + m * 16 + frow;
            af[m] = *(const short8*)&As[cur][R][ca * 8];
        }
        #pragma unroll
        for (int n = 0; n < 4; ++n) {
            const int R = wc * 64 + n * 16 + frow;
            bf[n] = frag8(*(const floatx4*)&Bs[cur][R][c0 * 4],
                          *(const floatx4*)&Bs[cur][R][c1 * 4]);
        }
        #pragma unroll
        for (int m = 0; m < 4; ++m)
            #pragma unroll
            for (int n = 0; n < 4; ++n)
                acc[m][n] = __builtin_amdgcn_mfma_f32_16x16x32_bf16(
                    af[m], bf[n], acc[m][n], 0, 0, 0);

        asm volatile("s_waitcnt lgkmcnt(0)" ::: "memory");
        __builtin_amdgcn_sched_barrier(0);
        __builtin_amdgcn_s_barrier();
    }
#undef STAGE_DN

    const int ccol  = lane & 15;
    const int crow0 = (lane >> 4) * 4;
    float* Ob = out + ((size_t)e * NT + (size_t)tm * 128) * NH + tn * 128;
    #pragma unroll
    for (int m = 0; m < 4; ++m)
        #pragma unroll
        for (int n = 0; n < 4; ++n)
            #pragma unroll
            for (int j = 0; j < 4; ++j) {
                const int row = wr * 64 + m * 16 + crow0 + j;
                const int col = wc * 64 + n * 16 + ccol;
                Ob[(size_t)row * NH + col] = acc[m][n][j];
            }
}

extern "C" void kernel_launch(void* const* d_in, const int* in_sizes, int n_in,
                              void* d_out, int out_size, void* d_ws, size_t ws_size,
                              hipStream_t stream) {
    const float* rin  = (const float*)d_in[0];
    const float* gate = (const float*)d_in[1];
    const float* up   = (const float*)d_in[2];
    const float* down = (const float*)d_in[3];
    float* out = (float*)d_out;
    ushort* hidden = (ushort*)d_ws;

    dim3 blk(256);
    moe_gateup<<<dim3(768), blk, 0, stream>>>(rin, gate, up, hidden);
    moe_down<<<dim3(2048), blk, 0, stream>>>(hidden, down, out);
}

// Round 5
// 387.615 us; speedup vs baseline: 1.2748x; 1.2748x over previous
//
#include <hip/hip_runtime.h>

// Qwen3 MoE experts: per-expert SwiGLU MLP.
//   gate = rin @ gate_proj^T ; up = rin @ up_proj^T
//   hidden = silu(gate) * up ; out = hidden @ down_proj^T
// E=32, T=512, H=2048, I=768. f32 inputs; bf16 MFMA, f32 accum.
// ws: hidden [E][T][I] bf16 = 24 MB.
//
// R4: gateup = bf16-in-LDS double buffer (48 KB total -> >=2 blocks/CU),
//     T14 reg-staging: global->VGPR loads issued one full compute phase
//     early; cvt_pk + swizzled ds_write_b128; single barrier per iter.
//     LDS chunk swizzle p=(c+(r>>1)+(r>>3))&3 -> <=2-way on read AND write.
//     moe_down unchanged from R3 (dbuf + gl_lds, it improved).

#define NE 32
#define NT 512
#define NH 2048
#define NI 768

typedef short        short8  __attribute__((ext_vector_type(8)));
typedef float        floatx4 __attribute__((ext_vector_type(4)));
typedef unsigned int uintx4  __attribute__((ext_vector_type(4)));
typedef __attribute__((address_space(1))) const unsigned int g_u32;
typedef __attribute__((address_space(3))) unsigned int l_u32;

__device__ __forceinline__ void gl_lds16(const void* g, void* l) {
    __builtin_amdgcn_global_load_lds((g_u32*)g, (l_u32*)l, 16, 0, 0);
}

__device__ __forceinline__ unsigned int cvt_pk_bf16(float lo, float hi) {
    unsigned int r;
    asm("v_cvt_pk_bf16_f32 %0, %1, %2" : "=v"(r) : "v"(lo), "v"(hi));
    return r;
}

__device__ __forceinline__ short8 frag8(floatx4 x0, floatx4 x1) {
    union { unsigned int u[4]; short8 s; } t;
    t.u[0] = cvt_pk_bf16(x0[0], x0[1]);
    t.u[1] = cvt_pk_bf16(x0[2], x0[3]);
    t.u[2] = cvt_pk_bf16(x1[0], x1[1]);
    t.u[3] = cvt_pk_bf16(x1[2], x1[3]);
    return t.s;
}

__device__ __forceinline__ uintx4 pack8(floatx4 x0, floatx4 x1) {
    uintx4 u;
    u[0] = cvt_pk_bf16(x0[0], x0[1]);
    u[1] = cvt_pk_bf16(x0[2], x0[3]);
    u[2] = cvt_pk_bf16(x1[0], x1[1]);
    u[3] = cvt_pk_bf16(x1[2], x1[3]);
    return u;
}

__device__ __forceinline__ ushort f2bf(float f) {
    union { float f; unsigned int u; } v; v.f = f;
    unsigned int r = v.u + 0x7fffu + ((v.u >> 16) & 1u);
    return (ushort)(r >> 16);
}

// chunk swizzle: row r, logical 16B-chunk c -> physical chunk
__device__ __forceinline__ int swz(int r, int c) {
    return (c + (r >> 1) + (r >> 3)) & 3;
}

// ---------------------------------------------------------------------------
// Kernel 1: fused gate+up + SwiGLU -> hidden(bf16).
// BM=128(T) x BN=128(I), BK=32 over H; 4 waves (2x2), 64x64/wave.
// LDS: 2 bufs x 3 tiles x ushort[128][32] = 48 KB.
// ---------------------------------------------------------------------------
__global__ __launch_bounds__(256, 2) void moe_gateup(
    const float* __restrict__ rin, const float* __restrict__ gate,
    const float* __restrict__ up, ushort* __restrict__ hidden)
{
    __shared__ ushort As[2][128][32];
    __shared__ ushort Gs[2][128][32];
    __shared__ ushort Us[2][128][32];

    const int bid = blockIdx.x;
    const int wg  = (bid & 7) * (768 / 8) + (bid >> 3);
    const int e   = wg / 24;
    const int rem = wg % 24;
    const int ti  = rem % 6;
    const int tm  = rem / 6;

    const int tid  = threadIdx.x;
    const int lane = tid & 63;
    const int wave = tid >> 6;
    const int wr = wave >> 1, wc = wave & 1;

    const float* Ab = rin  + (size_t)e * NT * NH + (size_t)(tm * 128) * NH;
    const float* Gb = gate + (size_t)e * NI * NH + (size_t)(ti * 128) * NH;
    const float* Ub = up   + (size_t)e * NI * NH + (size_t)(ti * 128) * NH;

    // staging map: wave stages rows [wave*32, wave*32+32) of all 3 tiles.
    // lane -> row = band + (lane>>1), K-half = (lane&1)*16 (f32), 4 float4.
    const int s_r  = wave * 32 + (lane >> 1);
    const int s_kh = (lane & 1) * 16;
    const int c_log0 = (lane & 1) * 2;           // first 16B bf16 chunk
    const int p0 = swz(s_r, c_log0);
    const int p1 = swz(s_r, c_log0 + 1);
    const float* Asrc = Ab + (size_t)s_r * NH + s_kh;
    const float* Gsrc = Gb + (size_t)s_r * NH + s_kh;
    const float* Usrc = Ub + (size_t)s_r * NH + s_kh;

    floatx4 accg[4][4], accu[4][4];
    #pragma unroll
    for (int m = 0; m < 4; ++m)
        #pragma unroll
        for (int n = 0; n < 4; ++n) {
            accg[m][n] = (floatx4)0.f;
            accu[m][n] = (floatx4)0.f;
        }

    const int frow = lane & 15;
    const int h    = lane >> 4;   // logical chunk for this lane's K range
    const int KT = NH / 32;

    floatx4 pa[4], pg[4], pu[4];  // prefetch registers (48 VGPR)

#define ISSUE(kt) do {                                                       \
        const int koff_ = (kt) * 32;                                         \
        _Pragma("unroll")                                                    \
        for (int i = 0; i < 4; ++i) {                                        \
            pa[i] = *(const floatx4*)(Asrc + koff_ + i * 4);                 \
            pg[i] = *(const floatx4*)(Gsrc + koff_ + i * 4);                 \
            pu[i] = *(const floatx4*)(Usrc + koff_ + i * 4);                 \
        }                                                                    \
        __builtin_amdgcn_sched_barrier(0);                                   \
    } while (0)

#define CVT_WRITE(b) do {                                                    \
        *(uintx4*)&As[b][s_r][p0 * 8] = pack8(pa[0], pa[1]);                 \
        *(uintx4*)&As[b][s_r][p1 * 8] = pack8(pa[2], pa[3]);                 \
        *(uintx4*)&Gs[b][s_r][p0 * 8] = pack8(pg[0], pg[1]);                 \
        *(uintx4*)&Gs[b][s_r][p1 * 8] = pack8(pg[2], pg[3]);                 \
        *(uintx4*)&Us[b][s_r][p0 * 8] = pack8(pu[0], pu[1]);                 \
        *(uintx4*)&Us[b][s_r][p1 * 8] = pack8(pu[2], pu[3]);                 \
    } while (0)

    // prologue: stage tile 0, issue loads for tile 1
    ISSUE(0);
    asm volatile("s_waitcnt vmcnt(0)" ::: "memory");
    CVT_WRITE(0);
    ISSUE(1);
    asm volatile("s_waitcnt lgkmcnt(0)" ::: "memory");
    __builtin_amdgcn_sched_barrier(0);
    __builtin_amdgcn_s_barrier();

    for (int kt = 0; kt < KT; ++kt) {
        const int cur = kt & 1;

        // ---- compute on buf[cur] ----
        short8 gf[4], uf[4];
        #pragma unroll
        for (int n = 0; n < 4; ++n) {
            const int R = wc * 64 + n * 16 + frow;
            const int p = swz(R, h);
            gf[n] = *(const short8*)&Gs[cur][R][p * 8];
            uf[n] = *(const short8*)&Us[cur][R][p * 8];
        }
        #pragma unroll
        for (int m = 0; m < 4; ++m) {
            const int R = wr * 64 + m * 16 + frow;
            const int p = swz(R, h);
            const short8 af = *(const short8*)&As[cur][R][p * 8];
            #pragma unroll
            for (int n = 0; n < 4; ++n) {
                accg[m][n] = __builtin_amdgcn_mfma_f32_16x16x32_bf16(
                    af, gf[n], accg[m][n], 0, 0, 0);
                accu[m][n] = __builtin_amdgcn_mfma_f32_16x16x32_bf16(
                    af, uf[n], accu[m][n], 0, 0, 0);
            }
        }

        // ---- stage tile kt+1 into buf[cur^1]; issue loads for kt+2 ----
        if (kt + 1 < KT) {
            asm volatile("s_waitcnt vmcnt(0)" ::: "memory");
            __builtin_amdgcn_sched_barrier(0);
            CVT_WRITE(cur ^ 1);
            if (kt + 2 < KT) ISSUE(kt + 2);
            asm volatile("s_waitcnt lgkmcnt(0)" ::: "memory");
            __builtin_amdgcn_sched_barrier(0);
            __builtin_amdgcn_s_barrier();
        }
    }
#undef ISSUE
#undef CVT_WRITE

    const int ccol  = lane & 15;
    const int crow0 = (lane >> 4) * 4;
    const size_t hbase = ((size_t)e * NT + (size_t)tm * 128) * NI + ti * 128;
    #pragma unroll
    for (int m = 0; m < 4; ++m)
        #pragma unroll
        for (int n = 0; n < 4; ++n)
            #pragma unroll
            for (int j = 0; j < 4; ++j) {
                const float g = accg[m][n][j];
                const float u = accu[m][n][j];
                const float hh = (g / (1.f + __expf(-g))) * u;
                const int row = wr * 64 + m * 16 + crow0 + j;
                const int col = wc * 64 + n * 16 + ccol;
                hidden[hbase + (size_t)row * NI + col] = f2bf(hh);
            }
}

// ---------------------------------------------------------------------------
// Kernel 2: down projection (unchanged from R3 — it improved with dbuf).
// A = hidden [T,I] bf16, B = down [H,I] f32. LDS 48 KB.
// ---------------------------------------------------------------------------
__global__ __launch_bounds__(256, 2) void moe_down(
    const ushort* __restrict__ hidden, const float* __restrict__ down,
    float* __restrict__ out)
{
    __shared__ ushort As[2][128][32];
    __shared__ float  Bs[2][128][32];

    const int bid = blockIdx.x;
    const int wg  = (bid & 7) * (2048 / 8) + (bid >> 3);
    const int e   = wg >> 6;
    const int rem = wg & 63;
    const int tn  = rem & 15;
    const int tm  = rem >> 4;

    const int tid  = threadIdx.x;
    const int lane = tid & 63;
    const int wave = tid >> 6;
    const int wr = wave >> 1, wc = wave & 1;

    const ushort* Ab = hidden + ((size_t)e * NT + (size_t)tm * 128) * NI;
    const float*  Bb = down + (size_t)e * NH * NI + (size_t)(tn * 128) * NI;

    floatx4 acc[4][4];
    #pragma unroll
    for (int m = 0; m < 4; ++m)
        #pragma unroll
        for (int n = 0; n < 4; ++n) acc[m][n] = (floatx4)0.f;

    const int frow = lane & 15;
    const int h    = lane >> 4;
    const int ca   = h ^ (frow & 3);
    const int rb   = frow & 7;
    const int c0   = (2 * h) ^ rb;
    const int c1   = (2 * h + 1) ^ rb;
    const int KT = NI / 32;

#define STAGE_DN(kt, b) do {                                                 \
        const int k0_ = (kt) * 32;                                           \
        _Pragma("unroll")                                                    \
        for (int i = 0; i < 2; ++i) {                                        \
            const int g_ = wave * 2 + i;                                     \
            const int r_ = g_ * 16 + (lane >> 2);                            \
            const int cs_ = (lane & 3) ^ (r_ & 3);                           \
            gl_lds16(Ab + (size_t)r_ * NI + k0_ + cs_ * 8, &As[b][g_ * 16][0]); \
        }                                                                    \
        _Pragma("unroll")                                                    \
        for (int i = 0; i < 4; ++i) {                                        \
            const int g_ = wave * 4 + i;                                     \
            const int r_ = g_ * 8 + (lane >> 3);                             \
            const int cs_ = (lane & 7) ^ (r_ & 7);                           \
            gl_lds16(Bb + (size_t)r_ * NI + k0_ + cs_ * 4, &Bs[b][g_ * 8][0]); \
        }                                                                    \
    } while (0)

    STAGE_DN(0, 0);

    for (int kt = 0; kt < KT; ++kt) {
        const int cur = kt & 1;
        if (kt + 1 < KT) {
            STAGE_DN(kt + 1, cur ^ 1);
            asm volatile("s_waitcnt vmcnt(6)" ::: "memory");
        } else {
            asm volatile("s_waitcnt vmcnt(0)" ::: "memory");
        }
        __builtin_amdgcn_s_barrier();

        short8 af[4], bf[4];
        #pragma unroll
        for (int m = 0; m < 4; ++m) {
            const int R = wr * 64 + m * 16 + frow;
            af[m] = *(const short8*)&As[cur][R][ca * 8];
        }
        #pragma unroll
        for (int n = 0; n < 4; ++n) {
            const int R = wc * 64 + n * 16 + frow;
            bf[n] = frag8(*(const floatx4*)&Bs[cur][R][c0 * 4],
                          *(const floatx4*)&Bs[cur][R][c1 * 4]);
        }
        #pragma unroll
        for (int m = 0; m < 4; ++m)
            #pragma unroll
            for (int n = 0; n < 4; ++n)
                acc[m][n] = __builtin_amdgcn_mfma_f32_16x16x32_bf16(
                    af[m], bf[n], acc[m][n], 0, 0, 0);

        asm volatile("s_waitcnt lgkmcnt(0)" ::: "memory");
        __builtin_amdgcn_sched_barrier(0);
        __builtin_amdgcn_s_barrier();
    }
#undef STAGE_DN

    const int ccol  = lane & 15;
    const int crow0 = (lane >> 4) * 4;
    float* Ob = out + ((size_t)e * NT + (size_t)tm * 128) * NH + tn * 128;
    #pragma unroll
    for (int m = 0; m < 4; ++m)
        #pragma unroll
        for (int n = 0; n < 4; ++n)
            #pragma unroll
            for (int j = 0; j < 4; ++j) {
                const int row = wr * 64 + m * 16 + crow0 + j;
                const int col = wc * 64 + n * 16 + ccol;
                Ob[(size_t)row * NH + col] = acc[m][n][j];
            }
}

extern "C" void kernel_launch(void* const* d_in, const int* in_sizes, int n_in,
                              void* d_out, int out_size, void* d_ws, size_t ws_size,
                              hipStream_t stream) {
    const float* rin  = (const float*)d_in[0];
    const float* gate = (const float*)d_in[1];
    const float* up   = (const float*)d_in[2];
    const float* down = (const float*)d_in[3];
    float* out = (float*)d_out;
    ushort* hidden = (ushort*)d_ws;

    dim3 blk(256);
    moe_gateup<<<dim3(768), blk, 0, stream>>>(rin, gate, up, hidden);
    moe_down<<<dim3(2048), blk, 0, stream>>>(hidden, down, out);
}